// Round 5
// baseline (74.250 us; speedup 1.0000x reference)
//
#include <hip/hip_runtime.h>
#include <math.h>

#define HID    1024
#define VOCAB  50257
#define MAXLEN 2048
#define LOGIT_BLOCKS ((VOCAB + 3) / 4)   // 12565
#define SMB 128                          // softmax_apply blocks
#define SMR (MAXLEN / SMB)               // 16 rows per block

// ---------------- ws layout (float indices) ----------------
// [0,     2048)   scores
// [4096,  5120)   attn_applied
// [5120,  6144)   x (post-relu)
// [6144,  9216)   gi
// [9216, 12288)   gh
// [12288,13312)   h_new (ws copy, float4-aligned)
// [13313]         lse
// [16384, 28949)  pm (per-logit-block max, 12565)
// [30720, 43285)  ps (per-logit-block sumexp, 12565)
// [49152,180224)  attn partials (128 x 1024)
#define WS_SCORES    0
#define WS_APPLIED   4096
#define WS_X         5120
#define WS_GI        6144
#define WS_GH        9216
#define WS_HNEW      12288
#define WS_LSE       13313
#define WS_PM        16384
#define WS_PS        30720
#define WS_PARTIALS  49152

__device__ inline float wave_reduce_sum(float v) {
    #pragma unroll
    for (int m = 32; m > 0; m >>= 1) v += __shfl_xor(v, m, 64);
    return v;
}

// K1: scores[l] = dot(cat(embedded, h), attn_W[l]) + attn_b[l]; one wave per row
__global__ __launch_bounds__(256) void k_attn_scores(
        const float* __restrict__ emb, const int* __restrict__ tok,
        const float* __restrict__ hidden,
        const float* __restrict__ attn_W, const float* __restrict__ attn_b,
        float* __restrict__ scores) {
    int gtid = blockIdx.x * blockDim.x + threadIdx.x;
    int row = gtid >> 6, lane = gtid & 63;
    if (row >= MAXLEN) return;
    const float* erow = emb + (size_t)tok[0] * HID;
    const float* wrow = attn_W + (size_t)row * (2 * HID);
    float acc = 0.f;
    #pragma unroll
    for (int i = 0; i < 8; ++i) {
        int k = i * 256 + lane * 4;
        float4 w = *(const float4*)(wrow + k);
        float4 c = (k < HID) ? *(const float4*)(erow + k)
                             : *(const float4*)(hidden + (k - HID));
        acc += w.x * c.x + w.y * c.y + w.z * c.z + w.w * c.w;
    }
    acc = wave_reduce_sum(acc);
    if (lane == 0) scores[row] = acc + attn_b[row];
}

// K2: fused softmax(2048) + partial weighted sum of encoder rows.
// Each of SMB blocks redundantly reduces the softmax stats (8 KB, L2-hot),
// then computes its SMR-row partial of attn_applied. Block 0 also writes
// attn_weights to d_out.
__global__ __launch_bounds__(256) void k_softmax_apply(
        const float* __restrict__ scores, const float* __restrict__ E,
        float* __restrict__ out_w, float* __restrict__ partials) {
    __shared__ float red[256];
    __shared__ float wrow[SMR];
    int t = threadIdx.x, b = blockIdx.x;
    float v[8];
    float m = -INFINITY;
    #pragma unroll
    for (int i = 0; i < 8; ++i) { v[i] = scores[t + 256 * i]; m = fmaxf(m, v[i]); }
    red[t] = m; __syncthreads();
    for (int s = 128; s > 0; s >>= 1) { if (t < s) red[t] = fmaxf(red[t], red[t + s]); __syncthreads(); }
    float M = red[0]; __syncthreads();
    float s = 0.f;
    #pragma unroll
    for (int i = 0; i < 8; ++i) s += expf(v[i] - M);
    red[t] = s; __syncthreads();
    for (int k = 128; k > 0; k >>= 1) { if (t < k) red[t] += red[t + k]; __syncthreads(); }
    float invS = 1.f / red[0];
    int r0 = b * SMR;
    if (t < SMR) wrow[t] = expf(scores[r0 + t] - M) * invS;
    __syncthreads();
    int j = t * 4;  // 1024 cols / 256 threads
    float4 acc = make_float4(0.f, 0.f, 0.f, 0.f);
    for (int r = 0; r < SMR; ++r) {
        float w = wrow[r];
        float4 e = *(const float4*)(E + (size_t)(r0 + r) * HID + j);
        acc.x += w * e.x; acc.y += w * e.y; acc.z += w * e.z; acc.w += w * e.w;
    }
    *(float4*)(partials + (size_t)b * HID + j) = acc;
    if (b == 0) {
        #pragma unroll
        for (int i = 0; i < 8; ++i) out_w[t + 256 * i] = expf(v[i] - M) * invS;
    }
}

// K3: reduce SMB partial rows -> attn_applied[1024]
__global__ __launch_bounds__(256) void k_apply_reduce(
        const float* __restrict__ partials, float* __restrict__ applied) {
    int j = blockIdx.x * blockDim.x + threadIdx.x;
    float acc = 0.f;
    for (int c = 0; c < SMB; ++c) acc += partials[(size_t)c * HID + j];
    applied[j] = acc;
}

// K4: x = relu(comb_W @ cat(embedded, attn_applied) + comb_b); one wave per row
__global__ __launch_bounds__(256) void k_comb(
        const float* __restrict__ emb, const int* __restrict__ tok,
        const float* __restrict__ applied,
        const float* __restrict__ comb_W, const float* __restrict__ comb_b,
        float* __restrict__ x) {
    int gtid = blockIdx.x * blockDim.x + threadIdx.x;
    int row = gtid >> 6, lane = gtid & 63;
    if (row >= HID) return;
    const float* erow = emb + (size_t)tok[0] * HID;
    const float* wrow = comb_W + (size_t)row * (2 * HID);
    float acc = 0.f;
    #pragma unroll
    for (int i = 0; i < 8; ++i) {
        int k = i * 256 + lane * 4;
        float4 w = *(const float4*)(wrow + k);
        float4 c = (k < HID) ? *(const float4*)(erow + k)
                             : *(const float4*)(applied + (k - HID));
        acc += w.x * c.x + w.y * c.y + w.z * c.z + w.w * c.w;
    }
    acc = wave_reduce_sum(acc);
    if (lane == 0) x[row] = fmaxf(acc + comb_b[row], 0.f);
}

// K5: gi = W_ih@x + b_ih, gh = W_hh@h + b_hh; 6144 rows, one wave per row
__global__ __launch_bounds__(256) void k_gru_gemv(
        const float* __restrict__ W_ih, const float* __restrict__ W_hh,
        const float* __restrict__ b_ih, const float* __restrict__ b_hh,
        const float* __restrict__ x, const float* __restrict__ h,
        float* __restrict__ gi, float* __restrict__ gh) {
    int gtid = blockIdx.x * blockDim.x + threadIdx.x;
    int row = gtid >> 6, lane = gtid & 63;
    if (row >= 6 * HID) return;
    const float* wrow; const float* vec;
    if (row < 3 * HID) { wrow = W_ih + (size_t)row * HID; vec = x; }
    else               { wrow = W_hh + (size_t)(row - 3 * HID) * HID; vec = h; }
    float acc = 0.f;
    #pragma unroll
    for (int i = 0; i < 4; ++i) {
        int k = i * 256 + lane * 4;
        float4 w = *(const float4*)(wrow + k);
        float4 c = *(const float4*)(vec + k);
        acc += w.x * c.x + w.y * c.y + w.z * c.z + w.w * c.w;
    }
    acc = wave_reduce_sum(acc);
    if (lane == 0) {
        if (row < 3 * HID) gi[row] = acc + b_ih[row];
        else               gh[row - 3 * HID] = acc + b_hh[row - 3 * HID];
    }
}

// K6: GRU gates -> h_new (d_out + ws copy)
__global__ __launch_bounds__(256) void k_gru_gate(
        const float* __restrict__ gi, const float* __restrict__ gh,
        const float* __restrict__ h,
        float* __restrict__ hnew_out, float* __restrict__ hnew_ws) {
    int i = blockIdx.x * blockDim.x + threadIdx.x;
    float r = 1.f / (1.f + expf(-(gi[i] + gh[i])));
    float z = 1.f / (1.f + expf(-(gi[i + HID] + gh[i + HID])));
    float n = tanhf(gi[i + 2 * HID] + r * gh[i + 2 * HID]);
    float hn = (1.f - z) * n + z * h[i];
    hnew_out[i] = hn;
    hnew_ws[i]  = hn;
}

// K7: logits + per-block online-LSE stats (m_b, s_b). One wave per row,
// 4 rows per block. No atomics, no global max dependency.
__global__ __launch_bounds__(256) void k_logits(
        const float* __restrict__ hnew, const float* __restrict__ out_W,
        const float* __restrict__ out_b,
        float* __restrict__ logits, float* __restrict__ pm, float* __restrict__ ps) {
    __shared__ float wl[4];
    int wib = threadIdx.x >> 6, lane = threadIdx.x & 63;
    int row = blockIdx.x * 4 + wib;
    float acc = 0.f;
    if (row < VOCAB) {
        const float* wrow = out_W + (size_t)row * HID;
        #pragma unroll
        for (int i = 0; i < 4; ++i) {
            int k = i * 256 + lane * 4;
            float4 w = *(const float4*)(wrow + k);
            float4 c = *(const float4*)(hnew + k);
            acc += w.x * c.x + w.y * c.y + w.z * c.z + w.w * c.w;
        }
        acc = wave_reduce_sum(acc);
        if (lane == 0) { acc += out_b[row]; logits[row] = acc; }
    }
    if (lane == 0) wl[wib] = (row < VOCAB) ? acc : -INFINITY;
    __syncthreads();
    if (threadIdx.x == 0) {
        float m = fmaxf(fmaxf(wl[0], wl[1]), fmaxf(wl[2], wl[3]));
        float s = expf(wl[0] - m) + expf(wl[1] - m) + expf(wl[2] - m) + expf(wl[3] - m);
        pm[blockIdx.x] = m;
        ps[blockIdx.x] = s;
    }
}

// K8: merge 12565 (m,s) pairs -> lse = M + log(sum s_b * exp(m_b - M))
__global__ __launch_bounds__(1024) void k_lse_finalize(
        const float* __restrict__ pm, const float* __restrict__ ps,
        float* __restrict__ lse) {
    __shared__ float red[1024];
    int t = threadIdx.x;
    float m = -INFINITY;
    for (int i = t; i < LOGIT_BLOCKS; i += 1024) m = fmaxf(m, pm[i]);
    red[t] = m; __syncthreads();
    for (int s = 512; s > 0; s >>= 1) { if (t < s) red[t] = fmaxf(red[t], red[t + s]); __syncthreads(); }
    float M = red[0]; __syncthreads();
    float acc = 0.f;
    for (int i = t; i < LOGIT_BLOCKS; i += 1024) acc += ps[i] * expf(pm[i] - M);
    red[t] = acc; __syncthreads();
    for (int s = 512; s > 0; s >>= 1) { if (t < s) red[t] += red[t + s]; __syncthreads(); }
    if (t == 0) lse[0] = M + logf(red[0]);
}

// K9: out[v] = logits[v] - lse  (in place on d_out)
__global__ __launch_bounds__(256) void k_writeout(float* __restrict__ out,
                                                  const float* __restrict__ lse) {
    int v = blockIdx.x * blockDim.x + threadIdx.x;
    if (v < VOCAB) out[v] -= lse[0];
}

extern "C" void kernel_launch(void* const* d_in, const int* in_sizes, int n_in,
                              void* d_out, int out_size, void* d_ws, size_t ws_size,
                              hipStream_t stream) {
    const int*   tok     = (const int*)d_in[0];
    const float* hidden  = (const float*)d_in[1];
    const float* E       = (const float*)d_in[2];
    const float* emb     = (const float*)d_in[3];
    const float* attn_W  = (const float*)d_in[4];
    const float* attn_b  = (const float*)d_in[5];
    const float* comb_W  = (const float*)d_in[6];
    const float* comb_b  = (const float*)d_in[7];
    const float* W_ih    = (const float*)d_in[8];
    const float* W_hh    = (const float*)d_in[9];
    const float* b_ih    = (const float*)d_in[10];
    const float* b_hh    = (const float*)d_in[11];
    const float* out_W   = (const float*)d_in[12];
    const float* out_b   = (const float*)d_in[13];

    float* out       = (float*)d_out;          // [0, VOCAB): log-probs
    float* hnew_out  = out + VOCAB;            // [VOCAB, VOCAB+HID): h_new
    float* attnw_out = out + VOCAB + HID;      // [.., +MAXLEN): attn_weights

    float* ws        = (float*)d_ws;
    float* scores    = ws + WS_SCORES;
    float* applied   = ws + WS_APPLIED;
    float* x         = ws + WS_X;
    float* gi        = ws + WS_GI;
    float* gh        = ws + WS_GH;
    float* hnew_ws   = ws + WS_HNEW;
    float* lse       = ws + WS_LSE;
    float* pm        = ws + WS_PM;
    float* ps        = ws + WS_PS;
    float* partials  = ws + WS_PARTIALS;

    k_attn_scores<<<MAXLEN / 4, 256, 0, stream>>>(emb, tok, hidden, attn_W, attn_b, scores);
    k_softmax_apply<<<SMB, 256, 0, stream>>>(scores, E, attnw_out, partials);
    k_apply_reduce<<<HID / 256, 256, 0, stream>>>(partials, applied);
    k_comb<<<HID / 4, 256, 0, stream>>>(emb, tok, applied, comb_W, comb_b, x);
    k_gru_gemv<<<(6 * HID) / 4, 256, 0, stream>>>(W_ih, W_hh, b_ih, b_hh, x, hidden, gi, gh);
    k_gru_gate<<<HID / 256, 256, 0, stream>>>(gi, gh, hidden, hnew_out, hnew_ws);
    k_logits<<<LOGIT_BLOCKS, 256, 0, stream>>>(hnew_ws, out_W, out_b, out, pm, ps);
    k_lse_finalize<<<1, 1024, 0, stream>>>(pm, ps, lse);
    k_writeout<<<(VOCAB + 255) / 256, 256, 0, stream>>>(out, lse);
}

// Round 6
// 69.271 us; speedup vs baseline: 1.0719x; 1.0719x over previous
//
#include <hip/hip_runtime.h>
#include <math.h>

#define HID    1024
#define VOCAB  50257
#define MAXLEN 2048
#define SMB 256                          // softmax_apply blocks
#define SMR (MAXLEN / SMB)               // 8 rows per block
#define LROWS 16                         // rows per logits block
#define LBLK ((VOCAB + LROWS - 1) / LROWS)  // 3142

// ---------------- ws layout (float indices) ----------------
// [0,     2048)   scores
// [4096,  5120)   attn_applied
// [5120,  6144)   x (post-relu)
// [6144,  9216)   gi
// [9216, 12288)   gh
// [12288,13312)   h_new (ws copy, float4-aligned)
// [16384, 19526)  pm (per-logit-block max, 3142)
// [30720, 33862)  ps (per-logit-block sumexp, 3142)
// [49152,311296)  attn partials (256 x 1024)
#define WS_SCORES    0
#define WS_APPLIED   4096
#define WS_X         5120
#define WS_GI        6144
#define WS_GH        9216
#define WS_HNEW      12288
#define WS_PM        16384
#define WS_PS        30720
#define WS_PARTIALS  49152

__device__ inline float wave_reduce_sum(float v) {
    #pragma unroll
    for (int m = 32; m > 0; m >>= 1) v += __shfl_xor(v, m, 64);
    return v;
}

// K1: scores[l] = dot(cat(embedded, h), attn_W[l]) + attn_b[l]; one wave per row
__global__ __launch_bounds__(256) void k_attn_scores(
        const float* __restrict__ emb, const int* __restrict__ tok,
        const float* __restrict__ hidden,
        const float* __restrict__ attn_W, const float* __restrict__ attn_b,
        float* __restrict__ scores) {
    int gtid = blockIdx.x * blockDim.x + threadIdx.x;
    int row = gtid >> 6, lane = gtid & 63;
    if (row >= MAXLEN) return;
    const float* erow = emb + (size_t)tok[0] * HID;
    const float* wrow = attn_W + (size_t)row * (2 * HID);
    float acc = 0.f;
    #pragma unroll
    for (int i = 0; i < 8; ++i) {
        int k = i * 256 + lane * 4;
        float4 w = *(const float4*)(wrow + k);
        float4 c = (k < HID) ? *(const float4*)(erow + k)
                             : *(const float4*)(hidden + (k - HID));
        acc += w.x * c.x + w.y * c.y + w.z * c.z + w.w * c.w;
    }
    acc = wave_reduce_sum(acc);
    if (lane == 0) scores[row] = acc + attn_b[row];
}

// K2: fused softmax(2048) + partial weighted sum of encoder rows.
// Each of SMB blocks redundantly reduces softmax stats (8 KB, cache-hot),
// then computes its SMR-row partial. Block 0 also writes attn_weights out.
__global__ __launch_bounds__(256) void k_softmax_apply(
        const float* __restrict__ scores, const float* __restrict__ E,
        float* __restrict__ out_w, float* __restrict__ partials) {
    __shared__ float red[256];
    __shared__ float wrow[SMR];
    int t = threadIdx.x, b = blockIdx.x;
    float v[8];
    float m = -INFINITY;
    #pragma unroll
    for (int i = 0; i < 8; ++i) { v[i] = scores[t + 256 * i]; m = fmaxf(m, v[i]); }
    red[t] = m; __syncthreads();
    for (int s = 128; s > 0; s >>= 1) { if (t < s) red[t] = fmaxf(red[t], red[t + s]); __syncthreads(); }
    float M = red[0]; __syncthreads();
    float s = 0.f;
    #pragma unroll
    for (int i = 0; i < 8; ++i) s += expf(v[i] - M);
    red[t] = s; __syncthreads();
    for (int k = 128; k > 0; k >>= 1) { if (t < k) red[t] += red[t + k]; __syncthreads(); }
    float invS = 1.f / red[0];
    int r0 = b * SMR;
    if (t < SMR) wrow[t] = expf(scores[r0 + t] - M) * invS;
    __syncthreads();
    int j = t * 4;  // 1024 cols / 256 threads
    float4 acc = make_float4(0.f, 0.f, 0.f, 0.f);
    #pragma unroll
    for (int r = 0; r < SMR; ++r) {
        float w = wrow[r];
        float4 e = *(const float4*)(E + (size_t)(r0 + r) * HID + j);
        acc.x += w * e.x; acc.y += w * e.y; acc.z += w * e.z; acc.w += w * e.w;
    }
    *(float4*)(partials + (size_t)b * HID + j) = acc;
    if (b == 0) {
        #pragma unroll
        for (int i = 0; i < 8; ++i) out_w[t + 256 * i] = expf(v[i] - M) * invS;
    }
}

// K3: reduce SMB partial rows -> applied[1024]; one block per column,
// 256-way parallel loads (latency-hiding), LDS tree.
__global__ __launch_bounds__(256) void k_apply_reduce(
        const float* __restrict__ partials, float* __restrict__ applied) {
    __shared__ float sm[4];
    int t = threadIdx.x, j = blockIdx.x;
    float v = partials[(size_t)t * HID + j];
    v = wave_reduce_sum(v);
    int wib = t >> 6, lane = t & 63;
    if (lane == 0) sm[wib] = v;
    __syncthreads();
    if (t == 0) applied[j] = sm[0] + sm[1] + sm[2] + sm[3];
}

// K4: x = relu(comb_W @ cat(embedded, attn_applied) + comb_b); one wave per row
__global__ __launch_bounds__(256) void k_comb(
        const float* __restrict__ emb, const int* __restrict__ tok,
        const float* __restrict__ applied,
        const float* __restrict__ comb_W, const float* __restrict__ comb_b,
        float* __restrict__ x) {
    int gtid = blockIdx.x * blockDim.x + threadIdx.x;
    int row = gtid >> 6, lane = gtid & 63;
    if (row >= HID) return;
    const float* erow = emb + (size_t)tok[0] * HID;
    const float* wrow = comb_W + (size_t)row * (2 * HID);
    float acc = 0.f;
    #pragma unroll
    for (int i = 0; i < 8; ++i) {
        int k = i * 256 + lane * 4;
        float4 w = *(const float4*)(wrow + k);
        float4 c = (k < HID) ? *(const float4*)(erow + k)
                             : *(const float4*)(applied + (k - HID));
        acc += w.x * c.x + w.y * c.y + w.z * c.z + w.w * c.w;
    }
    acc = wave_reduce_sum(acc);
    if (lane == 0) x[row] = fmaxf(acc + comb_b[row], 0.f);
}

// K5: gi = W_ih@x + b_ih, gh = W_hh@h + b_hh; 6144 rows, one wave per row
__global__ __launch_bounds__(256) void k_gru_gemv(
        const float* __restrict__ W_ih, const float* __restrict__ W_hh,
        const float* __restrict__ b_ih, const float* __restrict__ b_hh,
        const float* __restrict__ x, const float* __restrict__ h,
        float* __restrict__ gi, float* __restrict__ gh) {
    int gtid = blockIdx.x * blockDim.x + threadIdx.x;
    int row = gtid >> 6, lane = gtid & 63;
    if (row >= 6 * HID) return;
    const float* wrow; const float* vec;
    if (row < 3 * HID) { wrow = W_ih + (size_t)row * HID; vec = x; }
    else               { wrow = W_hh + (size_t)(row - 3 * HID) * HID; vec = h; }
    float acc = 0.f;
    #pragma unroll
    for (int i = 0; i < 4; ++i) {
        int k = i * 256 + lane * 4;
        float4 w = *(const float4*)(wrow + k);
        float4 c = *(const float4*)(vec + k);
        acc += w.x * c.x + w.y * c.y + w.z * c.z + w.w * c.w;
    }
    acc = wave_reduce_sum(acc);
    if (lane == 0) {
        if (row < 3 * HID) gi[row] = acc + b_ih[row];
        else               gh[row - 3 * HID] = acc + b_hh[row - 3 * HID];
    }
}

// K6: GRU gates -> h_new (d_out + ws copy)
__global__ __launch_bounds__(256) void k_gru_gate(
        const float* __restrict__ gi, const float* __restrict__ gh,
        const float* __restrict__ h,
        float* __restrict__ hnew_out, float* __restrict__ hnew_ws) {
    int i = blockIdx.x * blockDim.x + threadIdx.x;
    float r = 1.f / (1.f + expf(-(gi[i] + gh[i])));
    float z = 1.f / (1.f + expf(-(gi[i + HID] + gh[i + HID])));
    float n = tanhf(gi[i + 2 * HID] + r * gh[i + 2 * HID]);
    float hn = (1.f - z) * n + z * h[i];
    hnew_out[i] = hn;
    hnew_ws[i]  = hn;
}

// K7: logits + per-block online-LSE (m,s). 8 waves/block, 2 rows/wave.
__global__ __launch_bounds__(512) void k_logits(
        const float* __restrict__ hnew, const float* __restrict__ out_W,
        const float* __restrict__ out_b,
        float* __restrict__ logits, float* __restrict__ pm, float* __restrict__ ps) {
    __shared__ float wm[8], wsum[8];
    int wib = threadIdx.x >> 6, lane = threadIdx.x & 63;
    int r0 = blockIdx.x * LROWS + wib * 2;
    bool v0 = r0 < VOCAB, v1 = (r0 + 1) < VOCAB;
    int rr0 = v0 ? r0 : 0, rr1 = v1 ? (r0 + 1) : 0;
    const float* w0 = out_W + (size_t)rr0 * HID;
    const float* w1 = out_W + (size_t)rr1 * HID;
    float acc0 = 0.f, acc1 = 0.f;
    #pragma unroll
    for (int i = 0; i < 4; ++i) {
        int k = i * 256 + lane * 4;
        float4 a = *(const float4*)(w0 + k);
        float4 b = *(const float4*)(w1 + k);
        float4 c = *(const float4*)(hnew + k);
        acc0 += a.x * c.x + a.y * c.y + a.z * c.z + a.w * c.w;
        acc1 += b.x * c.x + b.y * c.y + b.z * c.z + b.w * c.w;
    }
    acc0 = wave_reduce_sum(acc0);
    acc1 = wave_reduce_sum(acc1);
    if (lane == 0) {
        float l0 = acc0 + out_b[rr0], l1 = acc1 + out_b[rr1];
        if (v0) logits[r0] = l0;
        if (v1) logits[r0 + 1] = l1;
        float m, s;
        if (v0 | v1) {
            float e0 = v0 ? l0 : -INFINITY, e1 = v1 ? l1 : -INFINITY;
            m = fmaxf(e0, e1);
            s = (v0 ? expf(e0 - m) : 0.f) + (v1 ? expf(e1 - m) : 0.f);
        } else { m = -INFINITY; s = 0.f; }
        wm[wib] = m; wsum[wib] = s;
    }
    __syncthreads();
    if (threadIdx.x == 0) {
        float M = wm[0];
        #pragma unroll
        for (int i = 1; i < 8; ++i) M = fmaxf(M, wm[i]);
        float S = 0.f;
        #pragma unroll
        for (int i = 0; i < 8; ++i) S += (wsum[i] > 0.f) ? wsum[i] * expf(wm[i] - M) : 0.f;
        pm[blockIdx.x] = M;
        ps[blockIdx.x] = S;
    }
}

// K8: every block redundantly merges the LBLK (m,s) pairs (bit-identical ->
// deterministic), then writes out[v] = logits[v] - lse for its slice.
__global__ __launch_bounds__(256) void k_logsoftmax_write(
        const float* __restrict__ pm, const float* __restrict__ ps,
        float* __restrict__ out) {
    __shared__ float red[256];
    int t = threadIdx.x;
    float m = -INFINITY;
    for (int i = t; i < LBLK; i += 256) m = fmaxf(m, pm[i]);
    red[t] = m; __syncthreads();
    for (int s = 128; s > 0; s >>= 1) { if (t < s) red[t] = fmaxf(red[t], red[t + s]); __syncthreads(); }
    float M = red[0]; __syncthreads();
    float acc = 0.f;
    for (int i = t; i < LBLK; i += 256) acc += ps[i] * expf(pm[i] - M);
    red[t] = acc; __syncthreads();
    for (int s = 128; s > 0; s >>= 1) { if (t < s) red[t] += red[t + s]; __syncthreads(); }
    float lse = M + logf(red[0]);
    int v = blockIdx.x * 256 + t;
    if (v < VOCAB) out[v] -= lse;
}

extern "C" void kernel_launch(void* const* d_in, const int* in_sizes, int n_in,
                              void* d_out, int out_size, void* d_ws, size_t ws_size,
                              hipStream_t stream) {
    const int*   tok     = (const int*)d_in[0];
    const float* hidden  = (const float*)d_in[1];
    const float* E       = (const float*)d_in[2];
    const float* emb     = (const float*)d_in[3];
    const float* attn_W  = (const float*)d_in[4];
    const float* attn_b  = (const float*)d_in[5];
    const float* comb_W  = (const float*)d_in[6];
    const float* comb_b  = (const float*)d_in[7];
    const float* W_ih    = (const float*)d_in[8];
    const float* W_hh    = (const float*)d_in[9];
    const float* b_ih    = (const float*)d_in[10];
    const float* b_hh    = (const float*)d_in[11];
    const float* out_W   = (const float*)d_in[12];
    const float* out_b   = (const float*)d_in[13];

    float* out       = (float*)d_out;          // [0, VOCAB): log-probs
    float* hnew_out  = out + VOCAB;            // [VOCAB, VOCAB+HID): h_new
    float* attnw_out = out + VOCAB + HID;      // [.., +MAXLEN): attn_weights

    float* ws        = (float*)d_ws;
    float* scores    = ws + WS_SCORES;
    float* applied   = ws + WS_APPLIED;
    float* x         = ws + WS_X;
    float* gi        = ws + WS_GI;
    float* gh        = ws + WS_GH;
    float* hnew_ws   = ws + WS_HNEW;
    float* pm        = ws + WS_PM;
    float* ps        = ws + WS_PS;
    float* partials  = ws + WS_PARTIALS;

    k_attn_scores<<<MAXLEN / 4, 256, 0, stream>>>(emb, tok, hidden, attn_W, attn_b, scores);
    k_softmax_apply<<<SMB, 256, 0, stream>>>(scores, E, attnw_out, partials);
    k_apply_reduce<<<HID, 256, 0, stream>>>(partials, applied);
    k_comb<<<HID / 4, 256, 0, stream>>>(emb, tok, applied, comb_W, comb_b, x);
    k_gru_gemv<<<(6 * HID) / 4, 256, 0, stream>>>(W_ih, W_hh, b_ih, b_hh, x, hidden, gi, gh);
    k_gru_gate<<<HID / 256, 256, 0, stream>>>(gi, gh, hidden, hnew_out, hnew_ws);
    k_logits<<<LBLK, 512, 0, stream>>>(hnew_ws, out_W, out_b, out, pm, ps);
    k_logsoftmax_write<<<(VOCAB + 255) / 256, 256, 0, stream>>>(pm, ps, out);
}